// Round 1
// baseline (1981.491 us; speedup 1.0000x reference)
//
#include <hip/hip_runtime.h>

#define B 512
#define L 1024
#define T 128
#define NROWS (L - 1)   /* 1023 bps rows */
#define SEG 64
#define NSEG 16         /* ceil(1023/64) */

typedef unsigned char u8;

// ---------------------------------------------------------------------------
// Kernel 1: forward Viterbi. One block per batch, thread j owns tag j.
// Exact fp32 op order: s = (prev[i] + obs[j]) + trans[i][j]; first-index argmax.
// ---------------------------------------------------------------------------
__global__ __launch_bounds__(T, 1) void viterbi_fwd(
    const float* __restrict__ emit, const float* __restrict__ trans,
    const float* __restrict__ w, float* __restrict__ out,
    u8* __restrict__ bps, int* __restrict__ lastTag)
{
    const int b = blockIdx.x;
    const int j = threadIdx.x;

    __shared__ __align__(16) float prevbuf[2][T];
    __shared__ float rv[T];
    __shared__ int   ri[T];

    // transitions column j -> registers (static indexing after full unroll)
    float tc[T];
#pragma unroll
    for (int i = 0; i < T; ++i) tc[i] = trans[i * T + j];

    const float wj = w[j];
    const size_t ebase = (size_t)b * L * T;

    float myprev = emit[ebase + j] * wj;   // t = 0, scaled like reference
    prevbuf[0][j] = myprev;
    u8* bprow = bps + (size_t)b * NROWS * T;
    __syncthreads();

    float raw_cur = emit[ebase + (size_t)T + j];   // emit[b][1][j]
    int bidx_prev = 0;
    int cur = 0;

    for (int t = 1; t < L; ++t) {
        // store previous step's bps row early; drains during the i-loop
        if (t >= 2) bprow[(size_t)(t - 2) * T + j] = (u8)bidx_prev;

        const int tn = (t + 1 < L) ? (t + 1) : (L - 1);
        const float raw_next = emit[ebase + (size_t)tn * T + j];
        const float obs = raw_cur * wj;

        const float4* p4 = (const float4*)prevbuf[cur];
        float b0 = -3.4e38f, b1 = -3.4e38f, b2 = -3.4e38f, b3 = -3.4e38f;
        int   i0 = 0, i1 = 0, i2 = 0, i3 = 0;
#pragma unroll
        for (int q = 0; q < T / 4; ++q) {
            const float4 p = p4[q];                 // LDS broadcast, conflict-free
            const float s0 = (p.x + obs) + tc[4 * q + 0];
            const float s1 = (p.y + obs) + tc[4 * q + 1];
            const float s2 = (p.z + obs) + tc[4 * q + 2];
            const float s3 = (p.w + obs) + tc[4 * q + 3];
            if (s0 > b0) { b0 = s0; i0 = 4 * q + 0; }
            if (s1 > b1) { b1 = s1; i1 = 4 * q + 1; }
            if (s2 > b2) { b2 = s2; i2 = 4 * q + 2; }
            if (s3 > b3) { b3 = s3; i3 = 4 * q + 3; }
        }
        // combine 4 chains; ties -> smaller index (numpy first-occurrence)
        float bv = b0; int bi = i0;
        if (b1 > bv || (b1 == bv && i1 < bi)) { bv = b1; bi = i1; }
        if (b2 > bv || (b2 == bv && i2 < bi)) { bv = b2; bi = i2; }
        if (b3 > bv || (b3 == bv && i3 < bi)) { bv = b3; bi = i3; }

        myprev = bv;
        prevbuf[cur ^ 1][j] = bv;
        bidx_prev = bi;
        __syncthreads();
        cur ^= 1;
        raw_cur = raw_next;
    }
    // final bps row (scan step 1022)
    bprow[(size_t)(NROWS - 1) * T + j] = (u8)bidx_prev;

    // reduce: best_score = max(prev_final), last = first-index argmax
    rv[j] = myprev; ri[j] = j;
    __syncthreads();
#pragma unroll
    for (int off = T / 2; off > 0; off >>= 1) {
        if (j < off) {
            const float a = rv[j], bb = rv[j + off];
            const int ia = ri[j], ib = ri[j + off];
            if (bb > a || (bb == a && ib < ia)) { rv[j] = bb; ri[j] = ib; }
        }
        __syncthreads();
    }
    if (j == 0) {
        out[(size_t)B * L + b] = rv[0];              // best_score[b]
        out[(size_t)b * L + (L - 1)] = (float)ri[0]; // path[b][L-1]
        lastTag[b] = ri[0];
    }
}

// ---------------------------------------------------------------------------
// Kernel 2: per-segment composed backpointer maps.
// comp[b][s][j] = tag at time s*64 given tag j at time min(s*64+64, 1023).
// ---------------------------------------------------------------------------
__global__ __launch_bounds__(T) void segcomp(const u8* __restrict__ bps,
                                             u8* __restrict__ comp)
{
    const int s = blockIdx.x & (NSEG - 1);
    const int b = blockIdx.x >> 4;
    const int r0 = s * SEG;
    const int cnt = (NROWS - r0 < SEG) ? (NROWS - r0) : SEG;

    __shared__ __align__(16) u8 rows[SEG * T];
    const uint4* src = (const uint4*)(bps + ((size_t)b * NROWS + r0) * T);
    uint4* dst = (uint4*)rows;
    const int nvec = cnt * (T / 16);
    for (int k = threadIdx.x; k < nvec; k += T) dst[k] = src[k];
    __syncthreads();

    int x = threadIdx.x;
    for (int k = cnt - 1; k >= 0; --k) x = rows[k * T + x];
    comp[((size_t)b * NSEG + s) * T + threadIdx.x] = (u8)x;
}

// ---------------------------------------------------------------------------
// Kernel 3: chain segment boundaries per batch (16 sequential hops).
// Writes path[b][s*64] for every segment s.
// ---------------------------------------------------------------------------
__global__ void chainseg(const u8* __restrict__ comp,
                         const int* __restrict__ lastTag,
                         float* __restrict__ out)
{
    const int b = blockIdx.x * blockDim.x + threadIdx.x;
    if (b >= B) return;
    int e = lastTag[b];
#pragma unroll 1
    for (int s = NSEG - 1; s >= 0; --s) {
        e = comp[((size_t)b * NSEG + s) * T + e];
        out[(size_t)b * L + s * SEG] = (float)e;
    }
}

// ---------------------------------------------------------------------------
// Kernel 4: fill segment interiors in parallel (64-step LDS chase each).
// ---------------------------------------------------------------------------
__global__ __launch_bounds__(T) void fillseg(const u8* __restrict__ bps,
                                             const int* __restrict__ lastTag,
                                             float* __restrict__ out)
{
    const int s = blockIdx.x & (NSEG - 1);
    const int b = blockIdx.x >> 4;
    const int r0 = s * SEG;
    const int cnt = (NROWS - r0 < SEG) ? (NROWS - r0) : SEG;

    __shared__ __align__(16) u8 rows[SEG * T];
    const uint4* src = (const uint4*)(bps + ((size_t)b * NROWS + r0) * T);
    uint4* dst = (uint4*)rows;
    const int nvec = cnt * (T / 16);
    for (int k = threadIdx.x; k < nvec; k += T) dst[k] = src[k];
    __syncthreads();

    if (threadIdx.x == 0) {
        int e = (s == NSEG - 1) ? lastTag[b]
                                : (int)out[(size_t)b * L + (size_t)(s + 1) * SEG];
        for (int k = cnt - 1; k >= 1; --k) {
            e = rows[k * T + e];
            out[(size_t)b * L + r0 + k] = (float)e;
        }
    }
}

// ---------------------------------------------------------------------------
extern "C" void kernel_launch(void* const* d_in, const int* in_sizes, int n_in,
                              void* d_out, int out_size, void* d_ws, size_t ws_size,
                              hipStream_t stream)
{
    const float* emit  = (const float*)d_in[0];
    const float* trans = (const float*)d_in[1];
    const float* w     = (const float*)d_in[2];
    float* out = (float*)d_out;

    u8*  bps     = (u8*)d_ws;                                   // 512*1023*128 B
    u8*  comp    = bps + (size_t)B * NROWS * T;                 // 512*16*128 B
    int* lastTag = (int*)(comp + (size_t)B * NSEG * T);         // 512*4 B

    viterbi_fwd<<<B, T, 0, stream>>>(emit, trans, w, out, bps, lastTag);
    segcomp<<<B * NSEG, T, 0, stream>>>(bps, comp);
    chainseg<<<2, 256, 0, stream>>>(comp, lastTag, out);
    fillseg<<<B * NSEG, T, 0, stream>>>(bps, lastTag, out);
}

// Round 2
// 1541.338 us; speedup vs baseline: 1.2856x; 1.2856x over previous
//
#include <hip/hip_runtime.h>

#define B 512
#define L 1024
#define T 128
#define NROWS (L - 1)   /* 1023 bps rows */
#define SEG 64
#define NSEG 16         /* ceil(1023/64) */

typedef unsigned char u8;

// ---------------------------------------------------------------------------
// Kernel 1: forward Viterbi, 4-way i-split.
// Block = 512 threads: h = tid&3 (i-quarter), j = tid>>2 (output tag).
// Exact fp32 op order: s = (prev[i] + obs[j]) + trans[i][j];
// numpy first-occurrence argmax (ascending visit + strict >, index tie-breaks
// at every merge).
// prevbuf is XOR-swizzled by 16B granule (phys = g ^ (g>>3), involutive) so
// the per-lane-quad reads hit 4 distinct bank groups (conflict-free).
// ---------------------------------------------------------------------------
__global__ __launch_bounds__(512, 4) void viterbi_fwd(
    const float* __restrict__ emit, const float* __restrict__ trans,
    const float* __restrict__ w, float* __restrict__ out,
    u8* __restrict__ bps, int* __restrict__ lastTag)
{
    const int b   = blockIdx.x;
    const int tid = threadIdx.x;
    const int h   = tid & 3;        // i-quarter
    const int j   = tid >> 2;       // output tag column
    const int hbase = h << 5;       // 32*h
    const bool lane0 = (h == 0);

    __shared__ __align__(16) float prevbuf[2 * T];  // 2 swizzled buffers, 512B each
    __shared__ float swv[8];
    __shared__ int   swj[8];

    // transitions for column j, rows [32h, 32h+32) -> 32 registers
    float tcr[32];
#pragma unroll
    for (int q = 0; q < 8; ++q)
#pragma unroll
        for (int e = 0; e < 4; ++e)
            tcr[4 * q + e] = trans[(size_t)(hbase + 4 * q + e) * T + j];

    const float wj = w[j];
    const size_t ebase = (size_t)b * L * T;
    u8* bprow = bps + (size_t)b * NROWS * T;

    // swizzled read base for this thread's quarter (8 float4 granules)
    const char* prd = (const char*)prevbuf + 128 * h;
    // swizzled write byte offset for column j
    char* pwr = (char*)prevbuf + 16 * ((j >> 2) ^ (j >> 5)) + 4 * (j & 3);

    // t = 0 init
    const float e0 = emit[ebase + j] * wj;
    if (lane0) *(float*)pwr = e0;           // buffer 0
    float myprev = e0;
    float raw_cur = emit[ebase + (size_t)T + j];  // emit[b][1][j]
    int bidx_prev = 0;
    __syncthreads();

#define STEP(T_, ROFF_, WOFF_)                                                 \
    {                                                                          \
        const int t_ = (T_);                                                   \
        if (lane0 && t_ >= 2)                                                  \
            bprow[(size_t)(t_ - 2) * T + j] = (u8)bidx_prev;                   \
        const int tn_ = (t_ + 1 < L) ? (t_ + 1) : (L - 1);                     \
        const float raw_next_ = emit[ebase + (size_t)tn_ * T + j];             \
        const float obs_ = raw_cur * wj;                                       \
        float b0 = -3.4e38f, b1 = -3.4e38f, b2 = -3.4e38f, b3 = -3.4e38f;      \
        int q0 = 0, q1 = 0, q2 = 0, q3 = 0;                                    \
        _Pragma("unroll")                                                      \
        for (int q = 0; q < 8; ++q) {                                          \
            const float4 p = *(const float4*)(prd + (ROFF_) + 16 * (q ^ h));   \
            const float s0 = (p.x + obs_) + tcr[4 * q + 0];                    \
            const float s1 = (p.y + obs_) + tcr[4 * q + 1];                    \
            const float s2 = (p.z + obs_) + tcr[4 * q + 2];                    \
            const float s3 = (p.w + obs_) + tcr[4 * q + 3];                    \
            if (s0 > b0) { b0 = s0; q0 = q; }                                  \
            if (s1 > b1) { b1 = s1; q1 = q; }                                  \
            if (s2 > b2) { b2 = s2; q2 = q; }                                  \
            if (s3 > b3) { b3 = s3; q3 = q; }                                  \
        }                                                                      \
        const int i0 = hbase + 4 * q0;                                         \
        const int i1 = hbase + 4 * q1 + 1;                                     \
        const int i2 = hbase + 4 * q2 + 2;                                     \
        const int i3 = hbase + 4 * q3 + 3;                                     \
        float bv = b0; int bi = i0;                                            \
        if (b1 > bv || (b1 == bv && i1 < bi)) { bv = b1; bi = i1; }            \
        if (b2 > bv || (b2 == bv && i2 < bi)) { bv = b2; bi = i2; }            \
        if (b3 > bv || (b3 == bv && i3 < bi)) { bv = b3; bi = i3; }            \
        float pv = __shfl_xor(bv, 1); int pi = __shfl_xor(bi, 1);              \
        if (pv > bv || (pv == bv && pi < bi)) { bv = pv; bi = pi; }            \
        pv = __shfl_xor(bv, 2); pi = __shfl_xor(bi, 2);                        \
        if (pv > bv || (pv == bv && pi < bi)) { bv = pv; bi = pi; }            \
        if (lane0) *(float*)(pwr + (WOFF_)) = bv;                              \
        myprev = bv;                                                           \
        bidx_prev = bi;                                                        \
        raw_cur = raw_next_;                                                   \
        __syncthreads();                                                       \
    }

    int t = 1;
    while (t + 1 < L) {          // pairs (1,2) .. (1021,1022)
        STEP(t, 0, 512)
        STEP(t + 1, 512, 0)
        t += 2;
    }
    STEP(1023, 0, 512)           // final step, reads buf0
#undef STEP

    // final bps row (scan step 1022)
    if (lane0) bprow[(size_t)(NROWS - 1) * T + j] = (u8)bidx_prev;

    // reduce best_score / last tag: within wave across j bits 0..3
    float rv = myprev; int rj = j;
#pragma unroll
    for (int m = 4; m <= 32; m <<= 1) {
        const float pv = __shfl_xor(rv, m);
        const int   pj = __shfl_xor(rj, m);
        if (pv > rv || (pv == rv && pj < rj)) { rv = pv; rj = pj; }
    }
    if ((tid & 63) == 0) { swv[tid >> 6] = rv; swj[tid >> 6] = rj; }
    __syncthreads();
    if (tid == 0) {
        float fv = swv[0]; int fj = swj[0];
#pragma unroll
        for (int wv = 1; wv < 8; ++wv) {
            if (swv[wv] > fv || (swv[wv] == fv && swj[wv] < fj)) {
                fv = swv[wv]; fj = swj[wv];
            }
        }
        out[(size_t)B * L + b] = fv;              // best_score[b]
        out[(size_t)b * L + (L - 1)] = (float)fj; // path[b][L-1]
        lastTag[b] = fj;
    }
}

// ---------------------------------------------------------------------------
// Kernel 2: per-segment composed backpointer maps.
// ---------------------------------------------------------------------------
__global__ __launch_bounds__(T) void segcomp(const u8* __restrict__ bps,
                                             u8* __restrict__ comp)
{
    const int s = blockIdx.x & (NSEG - 1);
    const int b = blockIdx.x >> 4;
    const int r0 = s * SEG;
    const int cnt = (NROWS - r0 < SEG) ? (NROWS - r0) : SEG;

    __shared__ __align__(16) u8 rows[SEG * T];
    const uint4* src = (const uint4*)(bps + ((size_t)b * NROWS + r0) * T);
    uint4* dst = (uint4*)rows;
    const int nvec = cnt * (T / 16);
    for (int k = threadIdx.x; k < nvec; k += T) dst[k] = src[k];
    __syncthreads();

    int x = threadIdx.x;
    for (int k = cnt - 1; k >= 0; --k) x = rows[k * T + x];
    comp[((size_t)b * NSEG + s) * T + threadIdx.x] = (u8)x;
}

// ---------------------------------------------------------------------------
// Kernel 3: chain segment boundaries per batch (16 sequential hops).
// ---------------------------------------------------------------------------
__global__ void chainseg(const u8* __restrict__ comp,
                         const int* __restrict__ lastTag,
                         float* __restrict__ out)
{
    const int b = blockIdx.x * blockDim.x + threadIdx.x;
    if (b >= B) return;
    int e = lastTag[b];
#pragma unroll 1
    for (int s = NSEG - 1; s >= 0; --s) {
        e = comp[((size_t)b * NSEG + s) * T + e];
        out[(size_t)b * L + s * SEG] = (float)e;
    }
}

// ---------------------------------------------------------------------------
// Kernel 4: fill segment interiors in parallel (64-step LDS chase each).
// ---------------------------------------------------------------------------
__global__ __launch_bounds__(T) void fillseg(const u8* __restrict__ bps,
                                             const int* __restrict__ lastTag,
                                             float* __restrict__ out)
{
    const int s = blockIdx.x & (NSEG - 1);
    const int b = blockIdx.x >> 4;
    const int r0 = s * SEG;
    const int cnt = (NROWS - r0 < SEG) ? (NROWS - r0) : SEG;

    __shared__ __align__(16) u8 rows[SEG * T];
    const uint4* src = (const uint4*)(bps + ((size_t)b * NROWS + r0) * T);
    uint4* dst = (uint4*)rows;
    const int nvec = cnt * (T / 16);
    for (int k = threadIdx.x; k < nvec; k += T) dst[k] = src[k];
    __syncthreads();

    if (threadIdx.x == 0) {
        int e = (s == NSEG - 1) ? lastTag[b]
                                : (int)out[(size_t)b * L + (size_t)(s + 1) * SEG];
        for (int k = cnt - 1; k >= 1; --k) {
            e = rows[k * T + e];
            out[(size_t)b * L + r0 + k] = (float)e;
        }
    }
}

// ---------------------------------------------------------------------------
extern "C" void kernel_launch(void* const* d_in, const int* in_sizes, int n_in,
                              void* d_out, int out_size, void* d_ws, size_t ws_size,
                              hipStream_t stream)
{
    const float* emit  = (const float*)d_in[0];
    const float* trans = (const float*)d_in[1];
    const float* w     = (const float*)d_in[2];
    float* out = (float*)d_out;

    u8*  bps     = (u8*)d_ws;                                   // 512*1023*128 B
    u8*  comp    = bps + (size_t)B * NROWS * T;                 // 512*16*128 B
    int* lastTag = (int*)(comp + (size_t)B * NSEG * T);         // 512*4 B

    viterbi_fwd<<<B, 512, 0, stream>>>(emit, trans, w, out, bps, lastTag);
    segcomp<<<B * NSEG, T, 0, stream>>>(bps, comp);
    chainseg<<<2, 256, 0, stream>>>(comp, lastTag, out);
    fillseg<<<B * NSEG, T, 0, stream>>>(bps, lastTag, out);
}

// Round 3
// 1286.556 us; speedup vs baseline: 1.5402x; 1.1980x over previous
//
#include <hip/hip_runtime.h>

#define B 512
#define L 1024
#define T 128
#define NROWS (L - 1)   /* 1023 bps rows */
#define SEG 64
#define NSEG 16         /* ceil(1023/64) */

typedef unsigned char u8;
typedef float f2 __attribute__((ext_vector_type(2)));

#define M3(a, b, c) fmaxf(fmaxf((a), (b)), (c))

// ---------------------------------------------------------------------------
// Kernel 1: forward Viterbi, 4-way i-split, packed-add + max3/rescan argmax.
// Block = 512 threads: h = tid&3 (i-quarter), j = tid>>2 (output tag).
// Exact fp32 op order: s = (prev[i] + obs[j]) + trans[i][j]  (v_pk_add_f32 is
// elementwise IEEE f32 add — bitwise identical).
// Argmax = value-max (max3 trees) + descending equality rescan; ties resolve
// to min index at every merge level == numpy first-occurrence.
// prevbuf XOR-swizzled by 16B granule (phys g = g ^ (g>>3)) -> conflict-free.
// ---------------------------------------------------------------------------
__global__ __launch_bounds__(512, 4) void viterbi_fwd(
    const float* __restrict__ emit, const float* __restrict__ trans,
    const float* __restrict__ w, float* __restrict__ out,
    u8* __restrict__ bps, int* __restrict__ lastTag)
{
    const int b   = blockIdx.x;
    const int tid = threadIdx.x;
    const int h   = tid & 3;        // i-quarter
    const int j   = tid >> 2;       // output tag column
    const int hbase = h << 5;       // 32*h
    const bool lane0 = (h == 0);
    const int INF = 0x7fffffff;

    __shared__ __align__(16) float prevbuf[2 * T];  // 2 swizzled buffers
    __shared__ float swv[8];
    __shared__ int   swj[8];

    // transitions for column j, rows [32h, 32h+32), packed as 16 float2
    f2 tc2[16];
#pragma unroll
    for (int q = 0; q < 8; ++q) {
        f2 a, c;
        a.x = trans[(size_t)(hbase + 4 * q + 0) * T + j];
        a.y = trans[(size_t)(hbase + 4 * q + 1) * T + j];
        c.x = trans[(size_t)(hbase + 4 * q + 2) * T + j];
        c.y = trans[(size_t)(hbase + 4 * q + 3) * T + j];
        tc2[2 * q] = a; tc2[2 * q + 1] = c;
    }

    const float wj = w[j];
    const size_t ebase = (size_t)b * L * T;
    u8* bprow = bps + (size_t)b * NROWS * T;

    // swizzled read base for this thread's quarter
    const char* prd = (const char*)prevbuf + 128 * h;
    // swizzled write byte offset for column j
    char* pwr = (char*)prevbuf + 16 * ((j >> 2) ^ (j >> 5)) + 4 * (j & 3);

    // t = 0 init
    const float e0 = emit[ebase + j] * wj;
    if (lane0) *(float*)pwr = e0;           // buffer 0
    float myprev = e0;
    float raw_cur = emit[ebase + (size_t)T + j];  // emit[b][1][j]
    int bidx_prev = 0;
    __syncthreads();

#define STEP(T_, ROFF_, WOFF_)                                                 \
    {                                                                          \
        const int t_ = (T_);                                                   \
        if (lane0 && t_ >= 2)                                                  \
            bprow[(size_t)(t_ - 2) * T + j] = (u8)bidx_prev;                   \
        const int tn_ = (t_ + 1 < L) ? (t_ + 1) : (L - 1);                     \
        const float raw_next_ = emit[ebase + (size_t)tn_ * T + j];             \
        const float obs_ = raw_cur * wj;                                       \
        f2 od_; od_.x = obs_; od_.y = obs_;                                    \
        f2 sv[16];                                                             \
        _Pragma("unroll")                                                      \
        for (int q = 0; q < 8; ++q) {                                          \
            const float4 p = *(const float4*)(prd + (ROFF_) + 16 * (q ^ h));   \
            f2 plo; plo.x = p.x; plo.y = p.y;                                  \
            f2 phi; phi.x = p.z; phi.y = p.w;                                  \
            sv[2 * q]     = (plo + od_) + tc2[2 * q];                          \
            sv[2 * q + 1] = (phi + od_) + tc2[2 * q + 1];                      \
        }                                                                      \
        float cm[4]; int loc[4];                                               \
        _Pragma("unroll")                                                      \
        for (int c = 0; c < 4; ++c) {                                          \
            const float s0 = sv[4 * c + 0].x, s1 = sv[4 * c + 0].y;            \
            const float s2 = sv[4 * c + 1].x, s3 = sv[4 * c + 1].y;            \
            const float s4 = sv[4 * c + 2].x, s5 = sv[4 * c + 2].y;            \
            const float s6 = sv[4 * c + 3].x, s7 = sv[4 * c + 3].y;            \
            const float m = M3(M3(s0, s1, s2), M3(s3, s4, s5),                 \
                               fmaxf(s6, s7));                                 \
            int k = 0;                                                         \
            k = (s7 == m) ? 7 : k; k = (s6 == m) ? 6 : k;                      \
            k = (s5 == m) ? 5 : k; k = (s4 == m) ? 4 : k;                      \
            k = (s3 == m) ? 3 : k; k = (s2 == m) ? 2 : k;                      \
            k = (s1 == m) ? 1 : k;                                             \
            cm[c] = m; loc[c] = 8 * c + k;                                     \
        }                                                                      \
        float bv = fmaxf(fmaxf(cm[0], cm[1]), fmaxf(cm[2], cm[3]));            \
        const int l0 = (cm[0] == bv) ? loc[0] : INF;                           \
        const int l1 = (cm[1] == bv) ? loc[1] : INF;                           \
        const int l2 = (cm[2] == bv) ? loc[2] : INF;                           \
        const int l3 = (cm[3] == bv) ? loc[3] : INF;                           \
        const int lm = min(min(min(l0, l1), l2), l3);                          \
        int gi = hbase + lm;                                                   \
        const float lv = bv;                                                   \
        bv = fmaxf(bv, __shfl_xor(bv, 1));                                     \
        bv = fmaxf(bv, __shfl_xor(bv, 2));                                     \
        int ii = (lv == bv) ? gi : INF;                                        \
        ii = min(ii, __shfl_xor(ii, 1));                                       \
        ii = min(ii, __shfl_xor(ii, 2));                                       \
        if (lane0) *(float*)(pwr + (WOFF_)) = bv;                              \
        myprev = bv;                                                           \
        bidx_prev = ii;                                                        \
        raw_cur = raw_next_;                                                   \
        __syncthreads();                                                       \
    }

    int t = 1;
    while (t + 1 < L) {          // pairs (1,2) .. (1021,1022)
        STEP(t, 0, 512)
        STEP(t + 1, 512, 0)
        t += 2;
    }
    STEP(1023, 0, 512)           // final step, reads buf0
#undef STEP

    // final bps row (scan step 1022)
    if (lane0) bprow[(size_t)(NROWS - 1) * T + j] = (u8)bidx_prev;

    // reduce best_score / last tag: within wave across j bits 0..3
    float rv = myprev; int rj = j;
#pragma unroll
    for (int m = 4; m <= 32; m <<= 1) {
        const float pv = __shfl_xor(rv, m);
        const int   pj = __shfl_xor(rj, m);
        if (pv > rv || (pv == rv && pj < rj)) { rv = pv; rj = pj; }
    }
    if ((tid & 63) == 0) { swv[tid >> 6] = rv; swj[tid >> 6] = rj; }
    __syncthreads();
    if (tid == 0) {
        float fv = swv[0]; int fj = swj[0];
#pragma unroll
        for (int wv = 1; wv < 8; ++wv) {
            if (swv[wv] > fv || (swv[wv] == fv && swj[wv] < fj)) {
                fv = swv[wv]; fj = swj[wv];
            }
        }
        out[(size_t)B * L + b] = fv;              // best_score[b]
        out[(size_t)b * L + (L - 1)] = (float)fj; // path[b][L-1]
        lastTag[b] = fj;
    }
}

// ---------------------------------------------------------------------------
// Kernel 2: per-segment composed backpointer maps.
// ---------------------------------------------------------------------------
__global__ __launch_bounds__(T) void segcomp(const u8* __restrict__ bps,
                                             u8* __restrict__ comp)
{
    const int s = blockIdx.x & (NSEG - 1);
    const int b = blockIdx.x >> 4;
    const int r0 = s * SEG;
    const int cnt = (NROWS - r0 < SEG) ? (NROWS - r0) : SEG;

    __shared__ __align__(16) u8 rows[SEG * T];
    const uint4* src = (const uint4*)(bps + ((size_t)b * NROWS + r0) * T);
    uint4* dst = (uint4*)rows;
    const int nvec = cnt * (T / 16);
    for (int k = threadIdx.x; k < nvec; k += T) dst[k] = src[k];
    __syncthreads();

    int x = threadIdx.x;
    for (int k = cnt - 1; k >= 0; --k) x = rows[k * T + x];
    comp[((size_t)b * NSEG + s) * T + threadIdx.x] = (u8)x;
}

// ---------------------------------------------------------------------------
// Kernel 3: chain segment boundaries per batch (16 sequential hops).
// ---------------------------------------------------------------------------
__global__ void chainseg(const u8* __restrict__ comp,
                         const int* __restrict__ lastTag,
                         float* __restrict__ out)
{
    const int b = blockIdx.x * blockDim.x + threadIdx.x;
    if (b >= B) return;
    int e = lastTag[b];
#pragma unroll 1
    for (int s = NSEG - 1; s >= 0; --s) {
        e = comp[((size_t)b * NSEG + s) * T + e];
        out[(size_t)b * L + s * SEG] = (float)e;
    }
}

// ---------------------------------------------------------------------------
// Kernel 4: fill segment interiors in parallel (64-step LDS chase each).
// ---------------------------------------------------------------------------
__global__ __launch_bounds__(T) void fillseg(const u8* __restrict__ bps,
                                             const int* __restrict__ lastTag,
                                             float* __restrict__ out)
{
    const int s = blockIdx.x & (NSEG - 1);
    const int b = blockIdx.x >> 4;
    const int r0 = s * SEG;
    const int cnt = (NROWS - r0 < SEG) ? (NROWS - r0) : SEG;

    __shared__ __align__(16) u8 rows[SEG * T];
    const uint4* src = (const uint4*)(bps + ((size_t)b * NROWS + r0) * T);
    uint4* dst = (uint4*)rows;
    const int nvec = cnt * (T / 16);
    for (int k = threadIdx.x; k < nvec; k += T) dst[k] = src[k];
    __syncthreads();

    if (threadIdx.x == 0) {
        int e = (s == NSEG - 1) ? lastTag[b]
                                : (int)out[(size_t)b * L + (size_t)(s + 1) * SEG];
        for (int k = cnt - 1; k >= 1; --k) {
            e = rows[k * T + e];
            out[(size_t)b * L + r0 + k] = (float)e;
        }
    }
}

// ---------------------------------------------------------------------------
extern "C" void kernel_launch(void* const* d_in, const int* in_sizes, int n_in,
                              void* d_out, int out_size, void* d_ws, size_t ws_size,
                              hipStream_t stream)
{
    const float* emit  = (const float*)d_in[0];
    const float* trans = (const float*)d_in[1];
    const float* w     = (const float*)d_in[2];
    float* out = (float*)d_out;

    u8*  bps     = (u8*)d_ws;                                   // 512*1023*128 B
    u8*  comp    = bps + (size_t)B * NROWS * T;                 // 512*16*128 B
    int* lastTag = (int*)(comp + (size_t)B * NSEG * T);         // 512*4 B

    viterbi_fwd<<<B, 512, 0, stream>>>(emit, trans, w, out, bps, lastTag);
    segcomp<<<B * NSEG, T, 0, stream>>>(bps, comp);
    chainseg<<<2, 256, 0, stream>>>(comp, lastTag, out);
    fillseg<<<B * NSEG, T, 0, stream>>>(bps, lastTag, out);
}